// Round 4
// baseline (593.646 us; speedup 1.0000x reference)
//
#include <hip/hip_runtime.h>

// Problem constants (B=4, L=4096, E=512, H=16, D=32)
#define EMBED  512
#define NHEAD  16
#define HDIM   32
#define NBATCH 4
#define SEQ    4096
#define NROWS  (NBATCH * SEQ)   // 16384
#define FEPS   1e-6f

typedef __attribute__((ext_vector_type(8))) short short8;
typedef __attribute__((ext_vector_type(4))) float f32x4;

// ---- bf16 split helpers (RNE) ----
__device__ __forceinline__ short f2bf(float x) {
    unsigned u = __float_as_uint(x);
    u += 0x7FFFu + ((u >> 16) & 1u);
    return (short)(u >> 16);
}
__device__ __forceinline__ float bf2f(short h) {
    return __uint_as_float(((unsigned)(unsigned short)h) << 16);
}

// ---- all 4 weights split in one launch: seg = blockIdx.x>>8 ----
__global__ __launch_bounds__(256)
void convert_w4(const float* __restrict__ W0, const float* __restrict__ W1,
                const float* __restrict__ W2, const float* __restrict__ W3,
                short* __restrict__ H0, short* __restrict__ L0,
                short* __restrict__ H1, short* __restrict__ L1,
                short* __restrict__ H2, short* __restrict__ L2,
                short* __restrict__ H3, short* __restrict__ L3) {
    const int seg = blockIdx.x >> 8;
    const int i = ((blockIdx.x & 255) * 256 + threadIdx.x) * 4;
    const float* W = (seg == 0) ? W0 : (seg == 1) ? W1 : (seg == 2) ? W2 : W3;
    short* H = (seg == 0) ? H0 : (seg == 1) ? H1 : (seg == 2) ? H2 : H3;
    short* L = (seg == 0) ? L0 : (seg == 1) ? L1 : (seg == 2) ? L2 : L3;
    float4 v = *(const float4*)(W + i);
    short4 h, l;
    h.x = f2bf(v.x); l.x = f2bf(v.x - bf2f(h.x));
    h.y = f2bf(v.y); l.y = f2bf(v.y - bf2f(h.y));
    h.z = f2bf(v.z); l.z = f2bf(v.z - bf2f(h.z));
    h.w = f2bf(v.w); l.w = f2bf(v.w - bf2f(h.w));
    *(short4*)(H + i) = h;
    *(short4*)(L + i) = l;
}

// ---- fused QKV projection GEMM: 3 ops x 512 blocks = 1536 blocks ---------
// op = lin>>9 selects (A, W, C). 128x128 tile, 4 waves in 2x2 (64x64 each),
// round-2 inner loop (VGPR staging + split at LDS write), y-major swizzle
// (same-bm blocks land on one XCD -> no cross-XCD A duplication).
// Epilogue: EPI per op (elu+1 for q/k, /SEQ for v), LDS transpose, split-bf16
// stores (hi+lo ushort4 = 16B/row-chunk, contiguous).
#define LDA 40   // padded LDS row (shorts): conflict-light

__global__ __launch_bounds__(256, 3)
void qkv_gemm(const float* __restrict__ Aq, const float* __restrict__ Ak,
              const float* __restrict__ Av,
              const short* __restrict__ WqH, const short* __restrict__ WqL,
              const short* __restrict__ WkH, const short* __restrict__ WkL,
              const short* __restrict__ WvH, const short* __restrict__ WvL,
              short* __restrict__ Qh, short* __restrict__ Ql,
              short* __restrict__ Kh, short* __restrict__ Kl,
              short* __restrict__ Vh, short* __restrict__ Vl) {
    __shared__ char smem[34048];                 // 20480 staging / 33792 epilogue
    short (*Ah)[LDA] = (short (*)[LDA])smem;
    short (*Al)[LDA] = (short (*)[LDA])(smem + 10240);

    const int tid  = threadIdx.x;
    const int lane = tid & 63;
    const int wave = tid >> 6;
    const int wm   = (wave >> 1) * 64;
    const int wn   = (wave & 1) * 64;
    const int l15  = lane & 15;
    const int kg   = lane >> 4;

    const int lin = blockIdx.x;
    const int op  = lin >> 9;                    // 0=q,1=k,2=v
    const int r_  = lin & 511;
    const int bn  = (r_ >> 7) * 128;             // y-major: same-bm 128 apart
    const int bm  = (r_ & 127) * 128;

    const float* A   = (op == 0) ? Aq  : (op == 1) ? Ak  : Av;
    const short* Whi = (op == 0) ? WqH : (op == 1) ? WkH : WvH;
    const short* Wlo = (op == 0) ? WqL : (op == 1) ? WkL : WvL;
    short* Ch = (op == 0) ? Qh : (op == 1) ? Kh : Vh;
    short* Cl = (op == 0) ? Ql : (op == 1) ? Kl : Vl;

    const int sr = tid >> 1;
    const int sk = (tid & 1) * 16;
    const float* Ap = A + (size_t)(bm + sr) * EMBED + sk;

    const short* Bh = Whi + (size_t)(bn + wn + l15) * EMBED + kg * 8;
    const short* Bl = Wlo + (size_t)(bn + wn + l15) * EMBED + kg * 8;

    f32x4 acc[4][4];
#pragma unroll
    for (int i = 0; i < 4; ++i)
#pragma unroll
        for (int j = 0; j < 4; ++j) acc[i][j] = (f32x4)0.0f;

#pragma unroll 1
    for (int k0 = 0; k0 < EMBED; k0 += 32) {
        float4 a0 = *(const float4*)(Ap + k0);
        float4 a1 = *(const float4*)(Ap + k0 + 4);
        float4 a2 = *(const float4*)(Ap + k0 + 8);
        float4 a3 = *(const float4*)(Ap + k0 + 12);
        short8 bh[4], bl[4];
#pragma unroll
        for (int j = 0; j < 4; ++j) {
            bh[j] = *(const short8*)(Bh + (size_t)j * 16 * EMBED + k0);
            bl[j] = *(const short8*)(Bl + (size_t)j * 16 * EMBED + k0);
        }
        __syncthreads();                         // prior LDS reads complete
        {
            float v[16] = {a0.x, a0.y, a0.z, a0.w, a1.x, a1.y, a1.z, a1.w,
                           a2.x, a2.y, a2.z, a2.w, a3.x, a3.y, a3.z, a3.w};
            short8 hv0, lv0, hv1, lv1;
#pragma unroll
            for (int q = 0; q < 8; ++q) {
                short hb = f2bf(v[q]);
                hv0[q] = hb; lv0[q] = f2bf(v[q] - bf2f(hb));
            }
#pragma unroll
            for (int q = 0; q < 8; ++q) {
                short hb = f2bf(v[8 + q]);
                hv1[q] = hb; lv1[q] = f2bf(v[8 + q] - bf2f(hb));
            }
            *(short8*)&Ah[sr][sk]     = hv0;
            *(short8*)&Ah[sr][sk + 8] = hv1;
            *(short8*)&Al[sr][sk]     = lv0;
            *(short8*)&Al[sr][sk + 8] = lv1;
        }
        __syncthreads();

        short8 ah[4], alr[4];
#pragma unroll
        for (int i = 0; i < 4; ++i) {
            ah[i]  = *(const short8*)&Ah[wm + i * 16 + l15][kg * 8];
            alr[i] = *(const short8*)&Al[wm + i * 16 + l15][kg * 8];
        }
#pragma unroll
        for (int i = 0; i < 4; ++i)
#pragma unroll
            for (int j = 0; j < 4; ++j) {
                acc[i][j] = __builtin_amdgcn_mfma_f32_16x16x32_bf16(ah[i],  bh[j], acc[i][j], 0, 0, 0);
                acc[i][j] = __builtin_amdgcn_mfma_f32_16x16x32_bf16(ah[i],  bl[j], acc[i][j], 0, 0, 0);
                acc[i][j] = __builtin_amdgcn_mfma_f32_16x16x32_bf16(alr[i], bh[j], acc[i][j], 0, 0, 0);
            }
    }

    // ---- epilogue: 2 passes of 32 rows, LDS transpose, split stores ----
    __syncthreads();                             // staging reads all done
    float* Cw = (float*)smem + wave * 2112;      // 32 x 66 floats per wave
#pragma unroll 1
    for (int pass = 0; pass < 2; ++pass) {
#pragma unroll
        for (int ii = 0; ii < 2; ++ii) {
            const int i = pass * 2 + ii;
#pragma unroll
            for (int j = 0; j < 4; ++j)
#pragma unroll
                for (int rr = 0; rr < 4; ++rr) {
                    float vv = acc[i][j][rr];
                    if (op < 2) vv = (vv > 0.f) ? (vv + 1.f) : __expf(vv);
                    else        vv = vv * (1.0f / (float)SEQ);
                    Cw[(ii * 16 + kg * 4 + rr) * 66 + j * 16 + l15] = vv;
                }
        }
#pragma unroll
        for (int inst = 0; inst < 8; ++inst) {
            f32x4 cv = *(const f32x4*)&Cw[(inst * 4 + kg) * 66 + l15 * 4];
            const int row = bm + wm + pass * 32 + inst * 4 + kg;
            ushort4 hi4, lo4;
            {
                short hb;
                hb = f2bf(cv[0]); hi4.x = (unsigned short)hb; lo4.x = (unsigned short)f2bf(cv[0] - bf2f(hb));
                hb = f2bf(cv[1]); hi4.y = (unsigned short)hb; lo4.y = (unsigned short)f2bf(cv[1] - bf2f(hb));
                hb = f2bf(cv[2]); hi4.z = (unsigned short)hb; lo4.z = (unsigned short)f2bf(cv[2] - bf2f(hb));
                hb = f2bf(cv[3]); hi4.w = (unsigned short)hb; lo4.w = (unsigned short)f2bf(cv[3] - bf2f(hb));
            }
            *(ushort4*)(Ch + (size_t)row * EMBED + bn + wn + l15 * 4) = hi4;
            *(ushort4*)(Cl + (size_t)row * EMBED + bn + wn + l15 * 4) = lo4;
        }
        __syncthreads();                         // pass-1 reads before pass-2 overwrite
    }
}

// ---- merge GEMM: C[m,n] = sum_k M[m,k]*Wm[n,k], M pre-split bf16 ---------
// 64x128 tile -> 1024 blocks (4/CU). 4 waves side by side in n (each 64m x 32n).
// No conversion anywhere: short8 staging -> LDS -> MFMA.
__global__ __launch_bounds__(256, 4)
void merge_gemm(const short* __restrict__ Ahg, const short* __restrict__ Alg,
                const short* __restrict__ Whi, const short* __restrict__ Wlo,
                float* __restrict__ C) {
    __shared__ char smem[34816];                 // 10240 staging / 34816 epilogue
    short (*Ahs)[LDA] = (short (*)[LDA])smem;    // 64 x 40
    short (*Als)[LDA] = (short (*)[LDA])(smem + 5120);

    const int tid  = threadIdx.x;
    const int lane = tid & 63;
    const int wave = tid >> 6;
    const int wn   = wave * 32;
    const int l15  = lane & 15;
    const int kg   = lane >> 4;

    const int lin = blockIdx.x;
    const int bm  = (lin & 255) * 64;            // y-major: same-bm 256 apart
    const int bn  = (lin >> 8) * 128;

    const int sr   = tid >> 2;                   // 0..63
    const int sseg = (tid & 3) * 8;              // 0,8,16,24
    const short* Aph = Ahg + (size_t)(bm + sr) * EMBED + sseg;
    const short* Apl = Alg + (size_t)(bm + sr) * EMBED + sseg;

    const short* Bh = Whi + (size_t)(bn + wn + l15) * EMBED + kg * 8;
    const short* Bl = Wlo + (size_t)(bn + wn + l15) * EMBED + kg * 8;

    f32x4 acc[4][2];
#pragma unroll
    for (int i = 0; i < 4; ++i)
#pragma unroll
        for (int j = 0; j < 2; ++j) acc[i][j] = (f32x4)0.0f;

#pragma unroll 1
    for (int k0 = 0; k0 < EMBED; k0 += 32) {
        short8 hx = *(const short8*)(Aph + k0);
        short8 lx = *(const short8*)(Apl + k0);
        short8 bh[2], bl[2];
#pragma unroll
        for (int j = 0; j < 2; ++j) {
            bh[j] = *(const short8*)(Bh + (size_t)j * 16 * EMBED + k0);
            bl[j] = *(const short8*)(Bl + (size_t)j * 16 * EMBED + k0);
        }
        __syncthreads();
        *(short8*)&Ahs[sr][sseg] = hx;
        *(short8*)&Als[sr][sseg] = lx;
        __syncthreads();

        short8 ah[4], alr[4];
#pragma unroll
        for (int i = 0; i < 4; ++i) {
            ah[i]  = *(const short8*)&Ahs[i * 16 + l15][kg * 8];
            alr[i] = *(const short8*)&Als[i * 16 + l15][kg * 8];
        }
#pragma unroll
        for (int i = 0; i < 4; ++i)
#pragma unroll
            for (int j = 0; j < 2; ++j) {
                acc[i][j] = __builtin_amdgcn_mfma_f32_16x16x32_bf16(ah[i],  bh[j], acc[i][j], 0, 0, 0);
                acc[i][j] = __builtin_amdgcn_mfma_f32_16x16x32_bf16(ah[i],  bl[j], acc[i][j], 0, 0, 0);
                acc[i][j] = __builtin_amdgcn_mfma_f32_16x16x32_bf16(alr[i], bh[j], acc[i][j], 0, 0, 0);
            }
    }

    // ---- epilogue: per-wave 64x34 LDS transpose -> contiguous fp32 stores --
    __syncthreads();
    float* Cw = (float*)smem + wave * 2176;      // 64 x 34 floats
#pragma unroll
    for (int i = 0; i < 4; ++i)
#pragma unroll
        for (int j = 0; j < 2; ++j)
#pragma unroll
            for (int rr = 0; rr < 4; ++rr)
                Cw[(i * 16 + kg * 4 + rr) * 34 + j * 16 + l15] = acc[i][j][rr];
#pragma unroll
    for (int inst = 0; inst < 8; ++inst) {
        const int rowl = inst * 8 + (lane >> 3);
        const int coll = (lane & 7) * 4;
        f32x4 cv = *(const f32x4*)&Cw[rowl * 34 + coll];
        *(float4*)(C + (size_t)(bm + rowl) * EMBED + bn + wn + coll) = *(float4*)&cv;
    }
}

// ---- KV + Ksum via MFMA, pre-split inputs (zero conversion) --------------
// KV[b,h] = K^T @ V (32x32 over s); Ksum fused via ones-B MFMA.
__global__ __launch_bounds__(256)
void kv_ksum_mfma(const short* __restrict__ Khg, const short* __restrict__ Klg,
                  const short* __restrict__ Vhg, const short* __restrict__ Vlg,
                  float* __restrict__ KV, float* __restrict__ Ksum) {
    __shared__ char smem[34816];
    short (*Khs)[34] = (short (*)[34])smem;
    short (*Kls)[34] = (short (*)[34])(smem + 8704);
    short (*Vhs)[34] = (short (*)[34])(smem + 17408);
    short (*Vls)[34] = (short (*)[34])(smem + 26112);

    const int bh_ = blockIdx.y;
    const int b = bh_ >> 4, h = bh_ & 15;
    const int s0 = blockIdx.x * 256;
    const int t = threadIdx.x;
    const int lane = t & 63, wave = t >> 6;
    const int l15 = lane & 15, kg = lane >> 4;
    const int ws = wave * 32;

    const int sl = t >> 1;
    const int dsel = (t & 1) * 16;

    f32x4 kvacc[2][2], ksacc[2];
#pragma unroll
    for (int i = 0; i < 2; ++i) {
        ksacc[i] = (f32x4)0.0f;
#pragma unroll
        for (int j = 0; j < 2; ++j) kvacc[i][j] = (f32x4)0.0f;
    }
    short8 ones;
#pragma unroll
    for (int q = 0; q < 8; ++q) ones[q] = (short)0x3F80;

#pragma unroll 1
    for (int it = 0; it < 2; ++it) {
        const size_t base = ((size_t)(b * SEQ + s0 + it * 128 + sl)) * EMBED + h * HDIM + dsel;
        short8 k0v = *(const short8*)(Khg + base);
        short8 k1v = *(const short8*)(Khg + base + 8);
        short8 l0v = *(const short8*)(Klg + base);
        short8 l1v = *(const short8*)(Klg + base + 8);
        short8 v0v = *(const short8*)(Vhg + base);
        short8 v1v = *(const short8*)(Vhg + base + 8);
        short8 w0v = *(const short8*)(Vlg + base);
        short8 w1v = *(const short8*)(Vlg + base + 8);
        __syncthreads();
        *(short8*)&Khs[sl][dsel] = k0v; *(short8*)&Khs[sl][dsel + 8] = k1v;
        *(short8*)&Kls[sl][dsel] = l0v; *(short8*)&Kls[sl][dsel + 8] = l1v;
        *(short8*)&Vhs[sl][dsel] = v0v; *(short8*)&Vhs[sl][dsel + 8] = v1v;
        *(short8*)&Vls[sl][dsel] = w0v; *(short8*)&Vls[sl][dsel + 8] = w1v;
        __syncthreads();

        short8 kah[2], kal[2], vbh[2], vbl[2];
#pragma unroll
        for (int i = 0; i < 2; ++i) {
#pragma unroll
            for (int q = 0; q < 8; ++q) {
                const int srow = ws + kg * 8 + q;
                const int col  = i * 16 + l15;
                kah[i][q] = Khs[srow][col];
                kal[i][q] = Kls[srow][col];
                vbh[i][q] = Vhs[srow][col];
                vbl[i][q] = Vls[srow][col];
            }
        }
#pragma unroll
        for (int i = 0; i < 2; ++i) {
#pragma unroll
            for (int j = 0; j < 2; ++j) {
                kvacc[i][j] = __builtin_amdgcn_mfma_f32_16x16x32_bf16(kah[i], vbh[j], kvacc[i][j], 0, 0, 0);
                kvacc[i][j] = __builtin_amdgcn_mfma_f32_16x16x32_bf16(kah[i], vbl[j], kvacc[i][j], 0, 0, 0);
                kvacc[i][j] = __builtin_amdgcn_mfma_f32_16x16x32_bf16(kal[i], vbh[j], kvacc[i][j], 0, 0, 0);
            }
            ksacc[i] = __builtin_amdgcn_mfma_f32_16x16x32_bf16(kah[i], ones, ksacc[i], 0, 0, 0);
            ksacc[i] = __builtin_amdgcn_mfma_f32_16x16x32_bf16(kal[i], ones, ksacc[i], 0, 0, 0);
        }
    }

    // ---- cross-wave reduce in LDS, one atomic per element ----
    __syncthreads();
    float* red = (float*)smem;                   // 4 x 1056 floats
    float* myred = red + wave * 1056;
#pragma unroll
    for (int i = 0; i < 2; ++i)
#pragma unroll
        for (int j = 0; j < 2; ++j)
#pragma unroll
            for (int rr = 0; rr < 4; ++rr)
                myred[(i * 16 + kg * 4 + rr) * 32 + j * 16 + l15] = kvacc[i][j][rr];
    if (l15 == 0) {
#pragma unroll
        for (int i = 0; i < 2; ++i)
#pragma unroll
            for (int rr = 0; rr < 4; ++rr)
                myred[1024 + i * 16 + kg * 4 + rr] = ksacc[i][rr];
    }
    __syncthreads();
    float* kvout = KV + (size_t)bh_ * 1024;
    for (int idx = t; idx < 1024; idx += 256) {
        float s4 = red[idx] + red[1056 + idx] + red[2112 + idx] + red[3168 + idx];
        atomicAdd(&kvout[idx], s4);
    }
    if (t < 32) {
        float s4 = red[1024 + t] + red[1056 + 1024 + t] + red[2112 + 1024 + t] + red[3168 + 1024 + t];
        atomicAdd(&Ksum[bh_ * 32 + t], s4);
    }
}

// ---- message: M[l,h,:] = (SEQ/(Q.Ksum+eps)) * Q @ KV[b,h], split I/O -----
__global__ __launch_bounds__(512)
void message_kernel(const short* __restrict__ Qh, const short* __restrict__ Ql,
                    const float* __restrict__ KV, const float* __restrict__ Ksum,
                    short* __restrict__ Mh, short* __restrict__ Ml) {
    const int row0 = blockIdx.x * 4;
    const int b    = row0 >> 12;
    const int t    = threadIdx.x;
    const int h    = t >> 5, e = t & 31;

    __shared__ float q[4][EMBED];
    __shared__ float ks[EMBED];
    ks[t] = Ksum[b * EMBED + t];
#pragma unroll
    for (int r = 0; r < 4; ++r) {
        const size_t idx = (size_t)(row0 + r) * EMBED + t;
        q[r][t] = bf2f(Qh[idx]) + bf2f(Ql[idx]);
    }

    const float* kvh = KV + (size_t)(b * NHEAD + h) * HDIM * HDIM + e;
    float kc[HDIM];
#pragma unroll
    for (int d = 0; d < HDIM; ++d) kc[d] = kvh[d * HDIM];
    __syncthreads();

#pragma unroll
    for (int r = 0; r < 4; ++r) {
        float zden = FEPS, m = 0.f;
#pragma unroll
        for (int d = 0; d < HDIM; ++d) {
            float qd = q[r][h * HDIM + d];
            zden = fmaf(qd, ks[h * HDIM + d], zden);
            m    = fmaf(qd, kc[d], m);
        }
        float res = m * ((float)SEQ / zden);
        const size_t idx = (size_t)(row0 + r) * EMBED + t;
        short hb = f2bf(res);
        Mh[idx] = hb;
        Ml[idx] = f2bf(res - bf2f(hb));
    }
}

// ---- launch ----
extern "C" void kernel_launch(void* const* d_in, const int* in_sizes, int n_in,
                              void* d_out, int out_size, void* d_ws, size_t ws_size,
                              hipStream_t stream) {
    const float* query = (const float*)d_in[0];
    const float* key   = (const float*)d_in[1];
    const float* value = (const float*)d_in[2];
    const float* Wq    = (const float*)d_in[3];
    const float* Wk    = (const float*)d_in[4];
    const float* Wv    = (const float*)d_in[5];
    const float* Wm    = (const float*)d_in[6];
    float* out = (float*)d_out;

    short* sws = (short*)d_ws;
    const size_t S = (size_t)NROWS * EMBED;       // 8.39M elems
    short* Qh = sws;         short* Ql = sws + S;
    short* Kh = sws + 2 * S; short* Kl = sws + 3 * S;
    short* Vh = sws + 4 * S; short* Vl = sws + 5 * S;
    short* Mh = Kh;          short* Ml = Kl;      // alias: K consumed before message
    float* KVb = (float*)(sws + 6 * S);           // 64*1024
    float* KSb = KVb + 64 * 1024;                 // 64*32
    short* wsp = (short*)(KSb + 64 * HDIM);
    const int WN = EMBED * EMBED;
    short* WqH = wsp;            short* WqL = wsp + WN;
    short* WkH = wsp + 2 * WN;   short* WkL = wsp + 3 * WN;
    short* WvH = wsp + 4 * WN;   short* WvL = wsp + 5 * WN;
    short* WmH = wsp + 6 * WN;   short* WmL = wsp + 7 * WN;

    hipMemsetAsync(KVb, 0, (64 * 1024 + 64 * HDIM) * sizeof(float), stream);

    convert_w4<<<1024, 256, 0, stream>>>(Wq, Wk, Wv, Wm,
                                         WqH, WqL, WkH, WkL,
                                         WvH, WvL, WmH, WmL);

    qkv_gemm<<<1536, 256, 0, stream>>>(query, key, value,
                                       WqH, WqL, WkH, WkL, WvH, WvL,
                                       Qh, Ql, Kh, Kl, Vh, Vl);

    kv_ksum_mfma<<<dim3(16, 64), 256, 0, stream>>>(Kh, Kl, Vh, Vl, KVb, KSb);
    message_kernel<<<NROWS / 4, 512, 0, stream>>>(Qh, Ql, KVb, KSb, Mh, Ml);

    merge_gemm<<<1024, 256, 0, stream>>>(Mh, Ml, WmH, WmL, out);
}

// Round 5
// 329.941 us; speedup vs baseline: 1.7992x; 1.7992x over previous
//
#include <hip/hip_runtime.h>

// Problem constants (B=4, L=4096, E=512, H=16, D=32)
#define EMBED  512
#define NHEAD  16
#define HDIM   32
#define NBATCH 4
#define SEQ    4096
#define NROWS  (NBATCH * SEQ)   // 16384
#define FEPS   1e-6f

typedef __attribute__((ext_vector_type(8))) short short8;
typedef __attribute__((ext_vector_type(4))) float f32x4;

// ---- bf16 split helpers (RNE) ----
__device__ __forceinline__ short f2bf(float x) {
    unsigned u = __float_as_uint(x);
    u += 0x7FFFu + ((u >> 16) & 1u);
    return (short)(u >> 16);
}
__device__ __forceinline__ float bf2f(short h) {
    return __uint_as_float(((unsigned)(unsigned short)h) << 16);
}

// ---- all 4 weights split in one launch: seg = blockIdx.x>>8 ----
__global__ __launch_bounds__(256)
void convert_w4(const float* __restrict__ W0, const float* __restrict__ W1,
                const float* __restrict__ W2, const float* __restrict__ W3,
                short* __restrict__ H0, short* __restrict__ L0,
                short* __restrict__ H1, short* __restrict__ L1,
                short* __restrict__ H2, short* __restrict__ L2,
                short* __restrict__ H3, short* __restrict__ L3) {
    const int seg = blockIdx.x >> 8;
    const int i = ((blockIdx.x & 255) * 256 + threadIdx.x) * 4;
    const float* W = (seg == 0) ? W0 : (seg == 1) ? W1 : (seg == 2) ? W2 : W3;
    short* H = (seg == 0) ? H0 : (seg == 1) ? H1 : (seg == 2) ? H2 : H3;
    short* L = (seg == 0) ? L0 : (seg == 1) ? L1 : (seg == 2) ? L2 : L3;
    float4 v = *(const float4*)(W + i);
    short4 h, l;
    h.x = f2bf(v.x); l.x = f2bf(v.x - bf2f(h.x));
    h.y = f2bf(v.y); l.y = f2bf(v.y - bf2f(h.y));
    h.z = f2bf(v.z); l.z = f2bf(v.z - bf2f(h.z));
    h.w = f2bf(v.w); l.w = f2bf(v.w - bf2f(h.w));
    *(short4*)(H + i) = h;
    *(short4*)(L + i) = l;
}

// ---- fused QKV projection GEMM -------------------------------------------
// Round-2 proven structure: 128x128 tile, 4 waves 2x2, (256,2) bounds, fp32
// direct scalar stores (WRITE == C size, measured). Fused: op = lin>>9 picks
// (A,W,C,epilogue); 1536 blocks => ~3 blocks/CU resident, no tail between ops.
// y-major swizzle (round-3, FETCH 66->40 MB): same-A blocks 128 apart -> same XCD.
#define LDA 40   // padded LDS row (shorts)

__global__ __launch_bounds__(256, 2)
void qkv_gemm(const float* __restrict__ Aq, const float* __restrict__ Ak,
              const float* __restrict__ Av,
              const short* __restrict__ WqH, const short* __restrict__ WqL,
              const short* __restrict__ WkH, const short* __restrict__ WkL,
              const short* __restrict__ WvH, const short* __restrict__ WvL,
              float* __restrict__ Qb, float* __restrict__ Kb,
              float* __restrict__ Vb) {
    __shared__ short Ah[128][LDA];
    __shared__ short Al[128][LDA];

    const int tid  = threadIdx.x;
    const int lane = tid & 63;
    const int wave = tid >> 6;
    const int wm   = (wave >> 1) * 64;
    const int wn   = (wave & 1) * 64;
    const int l15  = lane & 15;
    const int kg   = lane >> 4;

    const int lin = blockIdx.x;
    const int op  = lin >> 9;                    // 0=q,1=k,2=v
    const int r_  = lin & 511;
    const int bn  = (r_ >> 7) * 128;             // y-major swizzle
    const int bm  = (r_ & 127) * 128;

    const float* A   = (op == 0) ? Aq  : (op == 1) ? Ak  : Av;
    const short* Whi = (op == 0) ? WqH : (op == 1) ? WkH : WvH;
    const short* Wlo = (op == 0) ? WqL : (op == 1) ? WkL : WvL;
    float* C = (op == 0) ? Qb : (op == 1) ? Kb : Vb;

    // staging: thread loads A rows sr and sr+64, k-offset sk (8 fp32 each)
    const int sr = tid >> 2;
    const int sk = (tid & 3) * 8;
    const float* Ap0 = A + (size_t)(bm + sr) * EMBED + sk;
    const float* Ap1 = Ap0 + (size_t)64 * EMBED;

    const short* Bh = Whi + (size_t)(bn + wn + l15) * EMBED + kg * 8;
    const short* Bl = Wlo + (size_t)(bn + wn + l15) * EMBED + kg * 8;

    f32x4 acc[4][4];
#pragma unroll
    for (int i = 0; i < 4; ++i)
#pragma unroll
        for (int j = 0; j < 4; ++j) acc[i][j] = (f32x4)0.0f;

#pragma unroll 1
    for (int k0 = 0; k0 < EMBED; k0 += 32) {
        float4 a0 = *(const float4*)(Ap0 + k0);
        float4 a1 = *(const float4*)(Ap0 + k0 + 4);
        float4 a2 = *(const float4*)(Ap1 + k0);
        float4 a3 = *(const float4*)(Ap1 + k0 + 4);
        short8 bh[4], bl[4];
#pragma unroll
        for (int j = 0; j < 4; ++j) {
            bh[j] = *(const short8*)(Bh + (size_t)j * 16 * EMBED + k0);
            bl[j] = *(const short8*)(Bl + (size_t)j * 16 * EMBED + k0);
        }
        __syncthreads();   // protect previous iteration's LDS reads
        {
            float v[8] = {a0.x, a0.y, a0.z, a0.w, a1.x, a1.y, a1.z, a1.w};
            short8 hv, lv;
#pragma unroll
            for (int q = 0; q < 8; ++q) {
                short hb = f2bf(v[q]);
                hv[q] = hb; lv[q] = f2bf(v[q] - bf2f(hb));
            }
            *(short8*)&Ah[sr][sk] = hv;
            *(short8*)&Al[sr][sk] = lv;
        }
        {
            float v[8] = {a2.x, a2.y, a2.z, a2.w, a3.x, a3.y, a3.z, a3.w};
            short8 hv, lv;
#pragma unroll
            for (int q = 0; q < 8; ++q) {
                short hb = f2bf(v[q]);
                hv[q] = hb; lv[q] = f2bf(v[q] - bf2f(hb));
            }
            *(short8*)&Ah[sr + 64][sk] = hv;
            *(short8*)&Al[sr + 64][sk] = lv;
        }
        __syncthreads();

        short8 ah[4], alr[4];
#pragma unroll
        for (int i = 0; i < 4; ++i) {
            ah[i]  = *(const short8*)&Ah[wm + i * 16 + l15][kg * 8];
            alr[i] = *(const short8*)&Al[wm + i * 16 + l15][kg * 8];
        }
#pragma unroll
        for (int i = 0; i < 4; ++i)
#pragma unroll
            for (int j = 0; j < 4; ++j) {
                acc[i][j] = __builtin_amdgcn_mfma_f32_16x16x32_bf16(ah[i],  bh[j], acc[i][j], 0, 0, 0);
                acc[i][j] = __builtin_amdgcn_mfma_f32_16x16x32_bf16(ah[i],  bl[j], acc[i][j], 0, 0, 0);
                acc[i][j] = __builtin_amdgcn_mfma_f32_16x16x32_bf16(alr[i], bh[j], acc[i][j], 0, 0, 0);
            }
    }

    // epilogue: round-2 proven direct scalar stores (C/D layout col=lane&15,
    // row=(lane>>4)*4+r); measured WRITE == C size, no amplification.
#pragma unroll
    for (int i = 0; i < 4; ++i)
#pragma unroll
        for (int j = 0; j < 4; ++j) {
            const int col = bn + wn + j * 16 + l15;
#pragma unroll
            for (int r = 0; r < 4; ++r) {
                const int row = bm + wm + i * 16 + kg * 4 + r;
                float vv = acc[i][j][r];
                if (op < 2) vv = (vv > 0.f) ? (vv + 1.f) : __expf(vv);
                else        vv = vv * (1.0f / (float)SEQ);
                C[(size_t)row * EMBED + col] = vv;
            }
        }
}

// ---- merge GEMM: round-2 gemm_mfma<0> with y-major swizzle ----------------
__global__ __launch_bounds__(256, 2)
void merge_gemm(const float* __restrict__ A, const short* __restrict__ Whi,
                const short* __restrict__ Wlo, float* __restrict__ C) {
    __shared__ short Ah[128][LDA];
    __shared__ short Al[128][LDA];

    const int tid  = threadIdx.x;
    const int lane = tid & 63;
    const int wave = tid >> 6;
    const int wm   = (wave >> 1) * 64;
    const int wn   = (wave & 1) * 64;
    const int l15  = lane & 15;
    const int kg   = lane >> 4;

    const int lin = blockIdx.x;
    const int bn  = (lin >> 7) * 128;
    const int bm  = (lin & 127) * 128;

    const int sr = tid >> 2;
    const int sk = (tid & 3) * 8;
    const float* Ap0 = A + (size_t)(bm + sr) * EMBED + sk;
    const float* Ap1 = Ap0 + (size_t)64 * EMBED;

    const short* Bh = Whi + (size_t)(bn + wn + l15) * EMBED + kg * 8;
    const short* Bl = Wlo + (size_t)(bn + wn + l15) * EMBED + kg * 8;

    f32x4 acc[4][4];
#pragma unroll
    for (int i = 0; i < 4; ++i)
#pragma unroll
        for (int j = 0; j < 4; ++j) acc[i][j] = (f32x4)0.0f;

#pragma unroll 1
    for (int k0 = 0; k0 < EMBED; k0 += 32) {
        float4 a0 = *(const float4*)(Ap0 + k0);
        float4 a1 = *(const float4*)(Ap0 + k0 + 4);
        float4 a2 = *(const float4*)(Ap1 + k0);
        float4 a3 = *(const float4*)(Ap1 + k0 + 4);
        short8 bh[4], bl[4];
#pragma unroll
        for (int j = 0; j < 4; ++j) {
            bh[j] = *(const short8*)(Bh + (size_t)j * 16 * EMBED + k0);
            bl[j] = *(const short8*)(Bl + (size_t)j * 16 * EMBED + k0);
        }
        __syncthreads();
        {
            float v[8] = {a0.x, a0.y, a0.z, a0.w, a1.x, a1.y, a1.z, a1.w};
            short8 hv, lv;
#pragma unroll
            for (int q = 0; q < 8; ++q) {
                short hb = f2bf(v[q]);
                hv[q] = hb; lv[q] = f2bf(v[q] - bf2f(hb));
            }
            *(short8*)&Ah[sr][sk] = hv;
            *(short8*)&Al[sr][sk] = lv;
        }
        {
            float v[8] = {a2.x, a2.y, a2.z, a2.w, a3.x, a3.y, a3.z, a3.w};
            short8 hv, lv;
#pragma unroll
            for (int q = 0; q < 8; ++q) {
                short hb = f2bf(v[q]);
                hv[q] = hb; lv[q] = f2bf(v[q] - bf2f(hb));
            }
            *(short8*)&Ah[sr + 64][sk] = hv;
            *(short8*)&Al[sr + 64][sk] = lv;
        }
        __syncthreads();

        short8 ah[4], alr[4];
#pragma unroll
        for (int i = 0; i < 4; ++i) {
            ah[i]  = *(const short8*)&Ah[wm + i * 16 + l15][kg * 8];
            alr[i] = *(const short8*)&Al[wm + i * 16 + l15][kg * 8];
        }
#pragma unroll
        for (int i = 0; i < 4; ++i)
#pragma unroll
            for (int j = 0; j < 4; ++j) {
                acc[i][j] = __builtin_amdgcn_mfma_f32_16x16x32_bf16(ah[i],  bh[j], acc[i][j], 0, 0, 0);
                acc[i][j] = __builtin_amdgcn_mfma_f32_16x16x32_bf16(ah[i],  bl[j], acc[i][j], 0, 0, 0);
                acc[i][j] = __builtin_amdgcn_mfma_f32_16x16x32_bf16(alr[i], bh[j], acc[i][j], 0, 0, 0);
            }
    }

#pragma unroll
    for (int i = 0; i < 4; ++i)
#pragma unroll
        for (int j = 0; j < 4; ++j) {
            const int col = bn + wn + j * 16 + l15;
#pragma unroll
            for (int r = 0; r < 4; ++r) {
                const int row = bm + wm + i * 16 + kg * 4 + r;
                C[(size_t)row * EMBED + col] = acc[i][j][r];
            }
        }
}

// ---- KV + Ksum via split-bf16 MFMA (round-3 version, fp32 inputs) --------
__global__ __launch_bounds__(256)
void kv_ksum_mfma(const float* __restrict__ Kf, const float* __restrict__ Vf,
                  float* __restrict__ KV, float* __restrict__ Ksum) {
    __shared__ char smem[34816];
    short (*Kh)[34] = (short (*)[34])smem;
    short (*Kl)[34] = (short (*)[34])(smem + 8704);
    short (*Vh)[34] = (short (*)[34])(smem + 17408);
    short (*Vl)[34] = (short (*)[34])(smem + 26112);

    const int bh_ = blockIdx.y;
    const int b = bh_ >> 4, h = bh_ & 15;
    const int s0 = blockIdx.x * 256;
    const int t = threadIdx.x;
    const int lane = t & 63, wave = t >> 6;
    const int l15 = lane & 15, kg = lane >> 4;
    const int ws = wave * 32;

    const int sl = t >> 1;
    const int dsel = (t & 1) * 16;
    const float* Kbase = Kf + (size_t)b * SEQ * EMBED + h * HDIM;
    const float* Vbase = Vf + (size_t)b * SEQ * EMBED + h * HDIM;

    f32x4 kvacc[2][2], ksacc[2];
#pragma unroll
    for (int i = 0; i < 2; ++i) {
        ksacc[i] = (f32x4)0.0f;
#pragma unroll
        for (int j = 0; j < 2; ++j) kvacc[i][j] = (f32x4)0.0f;
    }
    short8 ones;
#pragma unroll
    for (int q = 0; q < 8; ++q) ones[q] = (short)0x3F80;   // bf16 1.0

    float4 kx[4], vx[4];
#pragma unroll
    for (int p = 0; p < 4; ++p) {
        kx[p] = *(const float4*)(Kbase + (size_t)(s0 + sl) * EMBED + dsel + 4 * p);
        vx[p] = *(const float4*)(Vbase + (size_t)(s0 + sl) * EMBED + dsel + 4 * p);
    }

#pragma unroll 1
    for (int it = 0; it < 2; ++it) {
        __syncthreads();
        {
            float kv_[8] = {kx[0].x, kx[0].y, kx[0].z, kx[0].w, kx[1].x, kx[1].y, kx[1].z, kx[1].w};
            float kv2[8] = {kx[2].x, kx[2].y, kx[2].z, kx[2].w, kx[3].x, kx[3].y, kx[3].z, kx[3].w};
            float vv_[8] = {vx[0].x, vx[0].y, vx[0].z, vx[0].w, vx[1].x, vx[1].y, vx[1].z, vx[1].w};
            float vv2[8] = {vx[2].x, vx[2].y, vx[2].z, vx[2].w, vx[3].x, vx[3].y, vx[3].z, vx[3].w};
            short8 h0, l0, h1, l1;
#pragma unroll
            for (int q = 0; q < 8; ++q) { short hb = f2bf(kv_[q]); h0[q] = hb; l0[q] = f2bf(kv_[q] - bf2f(hb)); }
#pragma unroll
            for (int q = 0; q < 8; ++q) { short hb = f2bf(kv2[q]); h1[q] = hb; l1[q] = f2bf(kv2[q] - bf2f(hb)); }
            *(short8*)&Kh[sl][dsel] = h0; *(short8*)&Kh[sl][dsel + 8] = h1;
            *(short8*)&Kl[sl][dsel] = l0; *(short8*)&Kl[sl][dsel + 8] = l1;
#pragma unroll
            for (int q = 0; q < 8; ++q) { short hb = f2bf(vv_[q]); h0[q] = hb; l0[q] = f2bf(vv_[q] - bf2f(hb)); }
#pragma unroll
            for (int q = 0; q < 8; ++q) { short hb = f2bf(vv2[q]); h1[q] = hb; l1[q] = f2bf(vv2[q] - bf2f(hb)); }
            *(short8*)&Vh[sl][dsel] = h0; *(short8*)&Vh[sl][dsel + 8] = h1;
            *(short8*)&Vl[sl][dsel] = l0; *(short8*)&Vl[sl][dsel + 8] = l1;
        }
        __syncthreads();
        if (it == 0) {
#pragma unroll
            for (int p = 0; p < 4; ++p) {
                kx[p] = *(const float4*)(Kbase + (size_t)(s0 + 128 + sl) * EMBED + dsel + 4 * p);
                vx[p] = *(const float4*)(Vbase + (size_t)(s0 + 128 + sl) * EMBED + dsel + 4 * p);
            }
        }
        short8 kah[2], kal[2], vbh[2], vbl[2];
#pragma unroll
        for (int i = 0; i < 2; ++i) {
#pragma unroll
            for (int q = 0; q < 8; ++q) {
                const int srow = ws + kg * 8 + q;
                const int col  = i * 16 + l15;
                kah[i][q] = Kh[srow][col];
                kal[i][q] = Kl[srow][col];
                vbh[i][q] = Vh[srow][col];
                vbl[i][q] = Vl[srow][col];
            }
        }
#pragma unroll
        for (int i = 0; i < 2; ++i) {
#pragma unroll
            for (int j = 0; j < 2; ++j) {
                kvacc[i][j] = __builtin_amdgcn_mfma_f32_16x16x32_bf16(kah[i], vbh[j], kvacc[i][j], 0, 0, 0);
                kvacc[i][j] = __builtin_amdgcn_mfma_f32_16x16x32_bf16(kah[i], vbl[j], kvacc[i][j], 0, 0, 0);
                kvacc[i][j] = __builtin_amdgcn_mfma_f32_16x16x32_bf16(kal[i], vbh[j], kvacc[i][j], 0, 0, 0);
            }
            ksacc[i] = __builtin_amdgcn_mfma_f32_16x16x32_bf16(kah[i], ones, ksacc[i], 0, 0, 0);
            ksacc[i] = __builtin_amdgcn_mfma_f32_16x16x32_bf16(kal[i], ones, ksacc[i], 0, 0, 0);
        }
    }

    __syncthreads();
    float* red = (float*)smem;
    float* myred = red + wave * 1056;
#pragma unroll
    for (int i = 0; i < 2; ++i)
#pragma unroll
        for (int j = 0; j < 2; ++j)
#pragma unroll
            for (int r = 0; r < 4; ++r)
                myred[(i * 16 + kg * 4 + r) * 32 + j * 16 + l15] = kvacc[i][j][r];
    if (l15 == 0) {
#pragma unroll
        for (int i = 0; i < 2; ++i)
#pragma unroll
            for (int r = 0; r < 4; ++r)
                myred[1024 + i * 16 + kg * 4 + r] = ksacc[i][r];
    }
    __syncthreads();
    float* kvout = KV + (size_t)bh_ * 1024;
    for (int idx = t; idx < 1024; idx += 256) {
        float s4 = red[idx] + red[1056 + idx] + red[2112 + idx] + red[3168 + idx];
        atomicAdd(&kvout[idx], s4);
    }
    if (t < 32) {
        float s4 = red[1024 + t] + red[1056 + 1024 + t] + red[2112 + 1024 + t] + red[3168 + 1024 + t];
        atomicAdd(&Ksum[bh_ * 32 + t], s4);
    }
}

// ---- message (in place): Q[l,h,:] <- (SEQ/(Q.Ksum+eps)) * Q @ KV[b,h] ----
__global__ __launch_bounds__(512)
void message_kernel(float* __restrict__ Q, const float* __restrict__ KV,
                    const float* __restrict__ Ksum) {
    const int blk  = blockIdx.x;
    const int row0 = blk * 4;
    const int b    = row0 >> 12;
    const int t    = threadIdx.x;
    const int h    = t >> 5, e = t & 31;

    __shared__ float q[4][EMBED];
    __shared__ float ks[EMBED];
    ks[t] = Ksum[b * EMBED + t];
#pragma unroll
    for (int r = 0; r < 4; ++r) q[r][t] = Q[(size_t)(row0 + r) * EMBED + t];

    const float* kvh = KV + (size_t)(b * NHEAD + h) * HDIM * HDIM + e;
    float kc[HDIM];
#pragma unroll
    for (int d = 0; d < HDIM; ++d) kc[d] = kvh[d * HDIM];
    __syncthreads();

#pragma unroll
    for (int r = 0; r < 4; ++r) {
        float zden = FEPS, m = 0.f;
#pragma unroll
        for (int d = 0; d < HDIM; ++d) {
            float qd = q[r][h * HDIM + d];
            zden = fmaf(qd, ks[h * HDIM + d], zden);
            m    = fmaf(qd, kc[d], m);
        }
        Q[(size_t)(row0 + r) * EMBED + t] = m * ((float)SEQ / zden);
    }
}

// ---- launch ----
extern "C" void kernel_launch(void* const* d_in, const int* in_sizes, int n_in,
                              void* d_out, int out_size, void* d_ws, size_t ws_size,
                              hipStream_t stream) {
    const float* query = (const float*)d_in[0];
    const float* key   = (const float*)d_in[1];
    const float* value = (const float*)d_in[2];
    const float* Wq    = (const float*)d_in[3];
    const float* Wk    = (const float*)d_in[4];
    const float* Wv    = (const float*)d_in[5];
    const float* Wm    = (const float*)d_in[6];
    float* out = (float*)d_out;

    float* ws  = (float*)d_ws;
    float* Qb  = ws;                              // 16384*512 fp32
    float* Kb  = Qb + (size_t)NROWS * EMBED;
    float* Vb  = Kb + (size_t)NROWS * EMBED;
    float* KVb = Vb + (size_t)NROWS * EMBED;      // 64*1024
    float* KSb = KVb + 64 * 1024;                 // 64*32
    short* wsp = (short*)(KSb + 64 * HDIM);
    const int WN = EMBED * EMBED;
    short* WqH = wsp;            short* WqL = wsp + WN;
    short* WkH = wsp + 2 * WN;   short* WkL = wsp + 3 * WN;
    short* WvH = wsp + 4 * WN;   short* WvL = wsp + 5 * WN;
    short* WmH = wsp + 6 * WN;   short* WmL = wsp + 7 * WN;

    hipMemsetAsync(KVb, 0, (64 * 1024 + 64 * HDIM) * sizeof(float), stream);

    convert_w4<<<1024, 256, 0, stream>>>(Wq, Wk, Wv, Wm,
                                         WqH, WqL, WkH, WkL,
                                         WvH, WvL, WmH, WmL);

    qkv_gemm<<<1536, 256, 0, stream>>>(query, key, value,
                                       WqH, WqL, WkH, WkL, WvH, WvL,
                                       Qb, Kb, Vb);

    kv_ksum_mfma<<<dim3(16, 64), 256, 0, stream>>>(Kb, Vb, KVb, KSb);
    message_kernel<<<NROWS / 4, 512, 0, stream>>>(Qb, KVb, KSb);

    merge_gemm<<<512, 256, 0, stream>>>(Qb, WmH, WmL, out);
}